// Round 6
// baseline (3382.792 us; speedup 1.0000x reference)
//
#include <hip/hip_runtime.h>
#include <hip/hip_bf16.h>

typedef __attribute__((ext_vector_type(8))) short bf16x8;
typedef __attribute__((ext_vector_type(4))) float f32x4;
typedef __attribute__((ext_vector_type(4))) int   i32x4;
typedef signed char i8;

#define N_ROWS 32768
#define K_KEYS 4096
#define DDIM   1024
#define BM 32
#define BK 128
#define NBLK (K_KEYS / BK)   /* 32 */
#define SP 132               /* Sx u32 pitch: ds_add 2-way, b128 read 4-way */
#define SC2 (1.52587890625e-05f) /* 2^-16 */

__device__ __forceinline__ ushort f2bf(float f) {
    __hip_bfloat16 b = __float2bfloat16(f);
    return *(ushort*)&b;
}
__device__ __forceinline__ float bf2f(ushort u) {
    __hip_bfloat16 b = *(__hip_bfloat16*)&u;
    return __bfloat162float(b);
}
__device__ __forceinline__ int clampi(int x) { return x > 127 ? 127 : (x < -127 ? -127 : x); }

// Pt swizzle (ushort units, 8-ushort granule XORed with row&7)
__device__ __forceinline__ int pidx(int r, int c_us) { return r * 128 + (c_us ^ ((r & 7) << 3)); }

// barrier that does NOT drain vmcnt: global prefetches stay in flight.
__device__ __forceinline__ void barrier_lgkm() {
    asm volatile("s_waitcnt lgkmcnt(0)" ::: "memory");
    __builtin_amdgcn_s_barrier();
    asm volatile("" ::: "memory");
}

// ---- prep: keys -> stream A (P1 operand): KH int8, tiles (g,c)=16 keys x 64 dims ----
__global__ void prep_ka(const float* __restrict__ keys, i8* __restrict__ sa) {
    int idx  = blockIdx.x * 256 + threadIdx.x;
    int lane = idx & 63, tile = idx >> 6;        // tile = g*16 + c
    int g = tile >> 4, c = tile & 15;
    int key = g * 16 + (lane & 15);
    int d0  = c * 64 + (lane >> 4) * 16;
    const float* s = keys + (size_t)key * DDIM + d0;
    union { i32x4 v; i8 b[16]; } u;
#pragma unroll
    for (int e = 0; e < 16; e++)
        u.b[e] = (i8)clampi((int)rintf(s[e] * 16.f));
    *(i32x4*)(sa + (size_t)tile * 1024 + lane * 16) = u.v;
}

// ---- prep: keys -> stream B (M2 operand): [KL,KH] interleaved ----
// A even byte = QH pairs with B even = KL; A odd = QL pairs with B odd = KH.
__global__ void prep_kb(const float* __restrict__ keys, i8* __restrict__ sb) {
    int idx  = blockIdx.x * 256 + threadIdx.x;
    int lane = idx & 63, tile = idx >> 6;        // tile = g*32 + m
    int g = tile >> 5, m = tile & 31;
    int key = g * 16 + (lane & 15);
    int d0  = m * 32 + (lane >> 4) * 8;
    const float* s = keys + (size_t)key * DDIM + d0;
    union { i32x4 v; i8 b[16]; } u;
#pragma unroll
    for (int e = 0; e < 8; e++) {
        float q = s[e];
        int h = clampi((int)rintf(q * 16.f));
        int l = clampi((int)rintf((q - (float)h * 0.0625f) * 4096.f));
        u.b[2 * e]     = (i8)l;   // KL pairs with QH
        u.b[2 * e + 1] = (i8)h;   // KH pairs with QL
    }
    *(i32x4*)(sb + (size_t)tile * 1024 + lane * 16) = u.v;
}

// ---- prep: values fp32 [K][D] -> packed V^T bf16 fragment tiles ----
__global__ void prep_vt(const float* __restrict__ v, ushort* __restrict__ vt) {
    __shared__ float t[32][33];
    const int tk = blockIdx.x;
    const int td = blockIdx.y;
    const int tx = threadIdx.x & 31;
    const int ty = threadIdx.x >> 5;
#pragma unroll
    for (int r = 0; r < 4; r++) {
        int k = tk * 32 + ty + 8 * r;
        t[ty + 8 * r][tx] = v[(size_t)k * DDIM + td * 32 + tx];
    }
    __syncthreads();
    if (threadIdx.x < 128) {
        int s    = threadIdx.x >> 6;
        int lane = threadIdx.x & 63;
        int l16  = lane & 15, lq = lane >> 4;
        int dg   = td * 2 + s;
        int dl   = s * 16 + l16;
        bf16x8 o;
#pragma unroll
        for (int e = 0; e < 8; e++)
            o[e] = (short)f2bf(t[lq * 8 + e][dl]);
        *(bf16x8*)(vt + ((size_t)dg * 128 + tk) * 512 + lane * 8) = o;
    }
}

// Fused flash kernel: d-split int8 QK, fixed-point ds_add S-reduction.
__launch_bounds__(512, 4)
__global__ void attn_main(const float* __restrict__ z,
                          const i8* __restrict__ sa,
                          const i8* __restrict__ sb,
                          const ushort* __restrict__ vtp,
                          float* __restrict__ out) {
    __shared__ unsigned Sx[BM][SP];       // 16896 B, fixed-point 2^-16
    __shared__ ushort Pt2[2][BM * 128];   // 16384 B
    __shared__ float  m_s[BM], l_s[BM], sc_s[BM];

    const int tid  = threadIdx.x;
    const int wave = tid >> 6;
    const int lane = tid & 63;
    const int l16  = lane & 15;
    const int lq   = lane >> 4;
    const int row0 = blockIdx.x * BM;

    // ---- Q int8-split fragments for this wave's 128 dims, in registers ----
    i32x4 qP1[2][2], qM2[2][4];
#pragma unroll
    for (int rg = 0; rg < 2; rg++) {
        int row = row0 + rg * 16 + l16;
        const float* zr = z + (size_t)row * DDIM + wave * 128;
#pragma unroll
        for (int c = 0; c < 2; c++) {
            union { i32x4 v; i8 b[16]; } u;
            const float* s = zr + c * 64 + lq * 16;
#pragma unroll
            for (int e = 0; e < 16; e++)
                u.b[e] = (i8)clampi((int)rintf(s[e] * 16.f));
            qP1[rg][c] = u.v;
        }
#pragma unroll
        for (int m = 0; m < 4; m++) {
            union { i32x4 v; i8 b[16]; } u;
            const float* s = zr + m * 32 + lq * 8;
#pragma unroll
            for (int e = 0; e < 8; e++) {
                float q = s[e];
                int h = clampi((int)rintf(q * 16.f));
                int l = clampi((int)rintf((q - (float)h * 0.0625f) * 4096.f));
                u.b[2 * e]     = (i8)h;   // QH pairs with KL
                u.b[2 * e + 1] = (i8)l;   // QL pairs with KH
            }
            qM2[rg][m] = u.v;
        }
    }
    if (tid < BM) { m_s[tid] = -1e30f; l_s[tid] = 0.f; }
    // zero the S accumulator
    for (int i = tid; i < BM * SP; i += 512)
        ((unsigned*)Sx)[i] = 0u;
    __syncthreads();

    f32x4 Oacc[2][8];
#pragma unroll
    for (int mt = 0; mt < 2; mt++)
#pragma unroll
        for (int nt = 0; nt < 8; nt++)
            Oacc[mt][nt] = (f32x4){0.f, 0.f, 0.f, 0.f};

    const i8* saB = sa + (size_t)wave * 2048 + lane * 16;
    const i8* sbB = sb + (size_t)wave * 4096 + lane * 16;
    const ushort* vtB = vtp + (size_t)wave * 524288 + lane * 8;

    i32x4 kA[2][2], kB[2][4];
#define LOADK8(gg, buf)                                                        \
    do {                                                                       \
        const i8* _a = saB + (size_t)(gg) * 16384;                             \
        const i8* _b = sbB + (size_t)(gg) * 32768;                             \
        kA[buf][0] = *(const i32x4*)_a;                                        \
        kA[buf][1] = *(const i32x4*)(_a + 1024);                               \
        kB[buf][0] = *(const i32x4*)_b;                                        \
        kB[buf][1] = *(const i32x4*)(_b + 1024);                               \
        kB[buf][2] = *(const i32x4*)(_b + 2048);                               \
        kB[buf][3] = *(const i32x4*)(_b + 3072);                               \
    } while (0)

    LOADK8(0, 0);

    for (int b = 0; b < NBLK; b++) {
        // ---- QK^T: per key-tile gt (16 keys), 12 int8 MFMAs over 128 dims ----
#pragma unroll
        for (int gt = 0; gt < 8; gt++) {
            const int cb = gt & 1, nb2 = cb ^ 1;
            if (gt < 7) {
                LOADK8(8 * b + gt + 1, nb2);
            } else {
                int gn = (b + 1 < NBLK) ? 8 * (b + 1) : 8 * b;
                LOADK8(gn, nb2);
            }
            i32x4 p1a = {0,0,0,0}, p1b = {0,0,0,0};
            i32x4 m2a0 = {0,0,0,0}, m2a1 = {0,0,0,0};
            i32x4 m2b0 = {0,0,0,0}, m2b1 = {0,0,0,0};
            p1a  = __builtin_amdgcn_mfma_i32_16x16x64_i8(qP1[0][0], kA[cb][0], p1a, 0, 0, 0);
            p1b  = __builtin_amdgcn_mfma_i32_16x16x64_i8(qP1[1][0], kA[cb][0], p1b, 0, 0, 0);
            m2a0 = __builtin_amdgcn_mfma_i32_16x16x64_i8(qM2[0][0], kB[cb][0], m2a0, 0, 0, 0);
            m2a1 = __builtin_amdgcn_mfma_i32_16x16x64_i8(qM2[1][0], kB[cb][0], m2a1, 0, 0, 0);
            m2b0 = __builtin_amdgcn_mfma_i32_16x16x64_i8(qM2[0][1], kB[cb][1], m2b0, 0, 0, 0);
            m2b1 = __builtin_amdgcn_mfma_i32_16x16x64_i8(qM2[1][1], kB[cb][1], m2b1, 0, 0, 0);
            p1a  = __builtin_amdgcn_mfma_i32_16x16x64_i8(qP1[0][1], kA[cb][1], p1a, 0, 0, 0);
            p1b  = __builtin_amdgcn_mfma_i32_16x16x64_i8(qP1[1][1], kA[cb][1], p1b, 0, 0, 0);
            m2a0 = __builtin_amdgcn_mfma_i32_16x16x64_i8(qM2[0][2], kB[cb][2], m2a0, 0, 0, 0);
            m2a1 = __builtin_amdgcn_mfma_i32_16x16x64_i8(qM2[1][2], kB[cb][2], m2a1, 0, 0, 0);
            m2b0 = __builtin_amdgcn_mfma_i32_16x16x64_i8(qM2[0][3], kB[cb][3], m2b0, 0, 0, 0);
            m2b1 = __builtin_amdgcn_mfma_i32_16x16x64_i8(qM2[1][3], kB[cb][3], m2b1, 0, 0, 0);

            const int col = gt * 16 + l16;
#pragma unroll
            for (int r = 0; r < 4; r++) {
                int fa = p1a[r] * 256 + m2a0[r] + m2b0[r];
                int fb = p1b[r] * 256 + m2a1[r] + m2b1[r];
                atomicAdd(&Sx[lq * 4 + r][col],      (unsigned)fa);
                atomicAdd(&Sx[16 + lq * 4 + r][col], (unsigned)fb);
            }
        }

        // vt kc=0 prefetch: lands during softmax
        bf16x8 vbuf[2][8];
        const ushort* vtI = vtB + (size_t)b * 2048;
#pragma unroll
        for (int nt = 0; nt < 8; nt++)
            vbuf[0][nt] = *(const bf16x8*)(vtI + nt * 65536);

        barrier_lgkm();

        // ---- softmax: thread (row, c0) owns cols [8c0, 8c0+8) ----
        {
            const int row = tid >> 4;
            const int c0  = tid & 15;
            i32x4 w0 = *(const i32x4*)&Sx[row][8 * c0];
            i32x4 w1 = *(const i32x4*)&Sx[row][8 * c0 + 4];
            // zero for next iteration (exclusive ownership, ordered by barrier2)
            *(i32x4*)&Sx[row][8 * c0]     = (i32x4){0,0,0,0};
            *(i32x4*)&Sx[row][8 * c0 + 4] = (i32x4){0,0,0,0};
            float sv[8];
#pragma unroll
            for (int j = 0; j < 4; j++) {
                sv[j]     = (float)w0[j] * SC2;
                sv[4 + j] = (float)w1[j] * SC2;
            }
            float mloc = sv[0];
#pragma unroll
            for (int j = 1; j < 8; j++) mloc = fmaxf(mloc, sv[j]);
#pragma unroll
            for (int off = 8; off >= 1; off >>= 1)
                mloc = fmaxf(mloc, __shfl_xor(mloc, off));
            float m_old = m_s[row];
            float m_new = fmaxf(m_old, mloc);
            float psum = 0.f;
            bf16x8 pb;
#pragma unroll
            for (int j = 0; j < 8; j++) {
                float p = __expf(sv[j] - m_new);
                psum += p;
                pb[j] = (short)f2bf(p);
            }
            *(bf16x8*)&Pt2[b & 1][pidx(row, 8 * c0)] = pb;
#pragma unroll
            for (int off = 8; off >= 1; off >>= 1)
                psum += __shfl_xor(psum, off);
            if (c0 == 0) {
                float sc = __expf(m_old - m_new);
                l_s[row] = l_s[row] * sc + psum;
                m_s[row] = m_new;
                sc_s[row] = sc;
            }
        }
        barrier_lgkm();

        // ---- rescale O, then PV over this key-block ----
        float sc0[4], sc1[4];
#pragma unroll
        for (int r = 0; r < 4; r++) {
            sc0[r] = sc_s[lq * 4 + r];
            sc1[r] = sc_s[16 + lq * 4 + r];
        }
#pragma unroll
        for (int nt = 0; nt < 8; nt++)
#pragma unroll
            for (int r = 0; r < 4; r++) {
                Oacc[0][nt][r] *= sc0[r];
                Oacc[1][nt][r] *= sc1[r];
            }

        const ushort* PtC = &Pt2[b & 1][0];
#pragma unroll
        for (int kc = 0; kc < 4; kc++) {
            if (kc < 3) {
#pragma unroll
                for (int nt = 0; nt < 8; nt++)
                    vbuf[(kc + 1) & 1][nt] = *(const bf16x8*)(vtI + nt * 65536 + (kc + 1) * 512);
            }
            bf16x8 pa0 = *(const bf16x8*)&PtC[pidx(l16, kc * 32 + lq * 8)];
            bf16x8 pa1 = *(const bf16x8*)&PtC[pidx(16 + l16, kc * 32 + lq * 8)];
#pragma unroll
            for (int nt = 0; nt < 8; nt++) {
                Oacc[0][nt] = __builtin_amdgcn_mfma_f32_16x16x32_bf16(pa0, vbuf[kc & 1][nt], Oacc[0][nt], 0, 0, 0);
                Oacc[1][nt] = __builtin_amdgcn_mfma_f32_16x16x32_bf16(pa1, vbuf[kc & 1][nt], Oacc[1][nt], 0, 0, 0);
            }
        }
    }
    __syncthreads();

    // ---- epilogue: normalize by l and store ----
    float li0[4], li1[4];
#pragma unroll
    for (int r = 0; r < 4; r++) {
        li0[r] = 1.f / l_s[lq * 4 + r];
        li1[r] = 1.f / l_s[16 + lq * 4 + r];
    }
#pragma unroll
    for (int nt = 0; nt < 8; nt++) {
#pragma unroll
        for (int r = 0; r < 4; r++) {
            int col = wave * 128 + nt * 16 + l16;
            int rowA = row0 + lq * 4 + r;
            out[(size_t)rowA * DDIM + col]        = Oacc[0][nt][r] * li0[r];
            out[(size_t)(rowA + 16) * DDIM + col] = Oacc[1][nt][r] * li1[r];
        }
    }
}

extern "C" void kernel_launch(void* const* d_in, const int* in_sizes, int n_in,
                              void* d_out, int out_size, void* d_ws, size_t ws_size,
                              hipStream_t stream) {
    const float* z    = (const float*)d_in[0];
    const float* keys = (const float*)d_in[1];
    const float* vals = (const float*)d_in[2];
    float* outp = (float*)d_out;

    i8* sa = (i8*)d_ws;                                    // 4 MB (P1 KH tiles)
    i8* sb = sa + (size_t)4 * 1024 * 1024;                 // 8 MB (M2 [KL,KH] tiles)
    ushort* vtw = (ushort*)(sb + (size_t)8 * 1024 * 1024); // 8 MB (V^T bf16 tiles)

    prep_ka<<<1024, 256, 0, stream>>>(keys, sa);
    prep_kb<<<2048, 256, 0, stream>>>(keys, sb);
    prep_vt<<<dim3(K_KEYS / 32, DDIM / 32), 256, 0, stream>>>(vals, vtw);
    attn_main<<<N_ROWS / BM, 512, 0, stream>>>(z, sa, sb, vtw, outp);
}

// Round 7
// 3372.628 us; speedup vs baseline: 1.0030x; 1.0030x over previous
//
#include <hip/hip_runtime.h>
#include <hip/hip_bf16.h>

typedef __attribute__((ext_vector_type(8))) short bf16x8;
typedef __attribute__((ext_vector_type(4))) float f32x4;
typedef __attribute__((ext_vector_type(4))) int   i32x4;
typedef signed char i8;

#define N_ROWS 32768
#define K_KEYS 4096
#define DDIM   1024
#define BM 32
#define BK 128
#define NBLK (K_KEYS / BK)   /* 32 */
#define SP 132               /* Sx u32 pitch: ds_add 2-way, b128 read 4-way */
#define SC2 (1.52587890625e-05f) /* 2^-16 */

__device__ __forceinline__ ushort f2bf(float f) {
    __hip_bfloat16 b = __float2bfloat16(f);
    return *(ushort*)&b;
}
__device__ __forceinline__ float bf2f(ushort u) {
    __hip_bfloat16 b = *(__hip_bfloat16*)&u;
    return __bfloat162float(b);
}
__device__ __forceinline__ int clampi(int x) { return x > 127 ? 127 : (x < -127 ? -127 : x); }

// Pt swizzle (ushort units, 8-ushort granule XORed with row&7)
__device__ __forceinline__ int pidx(int r, int c_us) { return r * 128 + (c_us ^ ((r & 7) << 3)); }

// barrier that does NOT drain vmcnt: global prefetches stay in flight.
__device__ __forceinline__ void barrier_lgkm() {
    asm volatile("s_waitcnt lgkmcnt(0)" ::: "memory");
    __builtin_amdgcn_s_barrier();
    asm volatile("" ::: "memory");
}

// ---- prep: keys -> stream A (P1 operand): KH int8, tiles (g,c)=16 keys x 64 dims ----
__global__ void prep_ka(const float* __restrict__ keys, i8* __restrict__ sa) {
    int idx  = blockIdx.x * 256 + threadIdx.x;
    int lane = idx & 63, tile = idx >> 6;        // tile = g*16 + c
    int g = tile >> 4, c = tile & 15;
    int key = g * 16 + (lane & 15);
    int d0  = c * 64 + (lane >> 4) * 16;
    const float* s = keys + (size_t)key * DDIM + d0;
    union { i32x4 v; i8 b[16]; } u;
#pragma unroll
    for (int e = 0; e < 16; e++)
        u.b[e] = (i8)clampi((int)rintf(s[e] * 16.f));
    *(i32x4*)(sa + (size_t)tile * 1024 + lane * 16) = u.v;
}

// ---- prep: keys -> stream B (M2 operand): [KL,KH] interleaved ----
// A even byte = QH pairs with B even = KL; A odd = QL pairs with B odd = KH.
__global__ void prep_kb(const float* __restrict__ keys, i8* __restrict__ sb) {
    int idx  = blockIdx.x * 256 + threadIdx.x;
    int lane = idx & 63, tile = idx >> 6;        // tile = g*32 + m
    int g = tile >> 5, m = tile & 31;
    int key = g * 16 + (lane & 15);
    int d0  = m * 32 + (lane >> 4) * 8;
    const float* s = keys + (size_t)key * DDIM + d0;
    union { i32x4 v; i8 b[16]; } u;
#pragma unroll
    for (int e = 0; e < 8; e++) {
        float q = s[e];
        int h = clampi((int)rintf(q * 16.f));
        int l = clampi((int)rintf((q - (float)h * 0.0625f) * 4096.f));
        u.b[2 * e]     = (i8)l;   // KL pairs with QH
        u.b[2 * e + 1] = (i8)h;   // KH pairs with QL
    }
    *(i32x4*)(sb + (size_t)tile * 1024 + lane * 16) = u.v;
}

// ---- prep: values fp32 [K][D] -> packed V^T bf16 fragment tiles ----
__global__ void prep_vt(const float* __restrict__ v, ushort* __restrict__ vt) {
    __shared__ float t[32][33];
    const int tk = blockIdx.x;
    const int td = blockIdx.y;
    const int tx = threadIdx.x & 31;
    const int ty = threadIdx.x >> 5;
#pragma unroll
    for (int r = 0; r < 4; r++) {
        int k = tk * 32 + ty + 8 * r;
        t[ty + 8 * r][tx] = v[(size_t)k * DDIM + td * 32 + tx];
    }
    __syncthreads();
    if (threadIdx.x < 128) {
        int s    = threadIdx.x >> 6;
        int lane = threadIdx.x & 63;
        int l16  = lane & 15, lq = lane >> 4;
        int dg   = td * 2 + s;
        int dl   = s * 16 + l16;
        bf16x8 o;
#pragma unroll
        for (int e = 0; e < 8; e++)
            o[e] = (short)f2bf(t[lq * 8 + e][dl]);
        *(bf16x8*)(vt + ((size_t)dg * 128 + tk) * 512 + lane * 8) = o;
    }
}

// Fused flash kernel: d-split int8 QK, fixed-point ds_add S-reduction.
// waves_per_eu(4,4): pin regalloc at the 128-VGPR / 4-waves-per-SIMD point —
// round 6 showed that an open max lets the allocator chase 8 waves/EU,
// squeeze to 64 VGPR, and spill everything to scratch (6.3 GB HBM traffic).
__global__ void __launch_bounds__(512)
__attribute__((amdgpu_waves_per_eu(4, 4)))
attn_main(const float* __restrict__ z,
          const i8* __restrict__ sa,
          const i8* __restrict__ sb,
          const ushort* __restrict__ vtp,
          float* __restrict__ out) {
    __shared__ unsigned Sx[BM][SP];       // 16896 B, fixed-point 2^-16
    __shared__ ushort Pt2[2][BM * 128];   // 16384 B
    __shared__ float  m_s[BM], l_s[BM], sc_s[BM];

    const int tid  = threadIdx.x;
    const int wave = tid >> 6;
    const int lane = tid & 63;
    const int l16  = lane & 15;
    const int lq   = lane >> 4;
    const int row0 = blockIdx.x * BM;

    // ---- Q int8-split fragments for this wave's 128 dims, in registers ----
    i32x4 qP1[2][2], qM2[2][4];
#pragma unroll
    for (int rg = 0; rg < 2; rg++) {
        int row = row0 + rg * 16 + l16;
        const float* zr = z + (size_t)row * DDIM + wave * 128;
#pragma unroll
        for (int c = 0; c < 2; c++) {
            union { i32x4 v; i8 b[16]; } u;
            const float* s = zr + c * 64 + lq * 16;
#pragma unroll
            for (int e = 0; e < 16; e++)
                u.b[e] = (i8)clampi((int)rintf(s[e] * 16.f));
            qP1[rg][c] = u.v;
        }
#pragma unroll
        for (int m = 0; m < 4; m++) {
            union { i32x4 v; i8 b[16]; } u;
            const float* s = zr + m * 32 + lq * 8;
#pragma unroll
            for (int e = 0; e < 8; e++) {
                float q = s[e];
                int h = clampi((int)rintf(q * 16.f));
                int l = clampi((int)rintf((q - (float)h * 0.0625f) * 4096.f));
                u.b[2 * e]     = (i8)h;   // QH pairs with KL
                u.b[2 * e + 1] = (i8)l;   // QL pairs with KH
            }
            qM2[rg][m] = u.v;
        }
    }
    if (tid < BM) { m_s[tid] = -1e30f; l_s[tid] = 0.f; }
    // zero the S accumulator
    for (int i = tid; i < BM * SP; i += 512)
        ((unsigned*)Sx)[i] = 0u;
    __syncthreads();

    f32x4 Oacc[2][8];
#pragma unroll
    for (int mt = 0; mt < 2; mt++)
#pragma unroll
        for (int nt = 0; nt < 8; nt++)
            Oacc[mt][nt] = (f32x4){0.f, 0.f, 0.f, 0.f};

    const i8* saB = sa + (size_t)wave * 2048 + lane * 16;
    const i8* sbB = sb + (size_t)wave * 4096 + lane * 16;
    const ushort* vtB = vtp + (size_t)wave * 524288 + lane * 8;

    i32x4 kA[2][2], kB[2][4];
#define LOADK8(gg, buf)                                                        \
    do {                                                                       \
        const i8* _a = saB + (size_t)(gg) * 16384;                             \
        const i8* _b = sbB + (size_t)(gg) * 32768;                             \
        kA[buf][0] = *(const i32x4*)_a;                                        \
        kA[buf][1] = *(const i32x4*)(_a + 1024);                               \
        kB[buf][0] = *(const i32x4*)_b;                                        \
        kB[buf][1] = *(const i32x4*)(_b + 1024);                               \
        kB[buf][2] = *(const i32x4*)(_b + 2048);                               \
        kB[buf][3] = *(const i32x4*)(_b + 3072);                               \
    } while (0)

    LOADK8(0, 0);

    for (int b = 0; b < NBLK; b++) {
        // ---- QK^T: per key-tile gt (16 keys), 12 int8 MFMAs over 128 dims ----
#pragma unroll
        for (int gt = 0; gt < 8; gt++) {
            const int cb = gt & 1, nb2 = cb ^ 1;
            if (gt < 7) {
                LOADK8(8 * b + gt + 1, nb2);
            } else {
                int gn = (b + 1 < NBLK) ? 8 * (b + 1) : 8 * b;
                LOADK8(gn, nb2);
            }
            i32x4 p1a = {0,0,0,0}, p1b = {0,0,0,0};
            i32x4 m2a0 = {0,0,0,0}, m2a1 = {0,0,0,0};
            i32x4 m2b0 = {0,0,0,0}, m2b1 = {0,0,0,0};
            p1a  = __builtin_amdgcn_mfma_i32_16x16x64_i8(qP1[0][0], kA[cb][0], p1a, 0, 0, 0);
            p1b  = __builtin_amdgcn_mfma_i32_16x16x64_i8(qP1[1][0], kA[cb][0], p1b, 0, 0, 0);
            m2a0 = __builtin_amdgcn_mfma_i32_16x16x64_i8(qM2[0][0], kB[cb][0], m2a0, 0, 0, 0);
            m2a1 = __builtin_amdgcn_mfma_i32_16x16x64_i8(qM2[1][0], kB[cb][0], m2a1, 0, 0, 0);
            m2b0 = __builtin_amdgcn_mfma_i32_16x16x64_i8(qM2[0][1], kB[cb][1], m2b0, 0, 0, 0);
            m2b1 = __builtin_amdgcn_mfma_i32_16x16x64_i8(qM2[1][1], kB[cb][1], m2b1, 0, 0, 0);
            p1a  = __builtin_amdgcn_mfma_i32_16x16x64_i8(qP1[0][1], kA[cb][1], p1a, 0, 0, 0);
            p1b  = __builtin_amdgcn_mfma_i32_16x16x64_i8(qP1[1][1], kA[cb][1], p1b, 0, 0, 0);
            m2a0 = __builtin_amdgcn_mfma_i32_16x16x64_i8(qM2[0][2], kB[cb][2], m2a0, 0, 0, 0);
            m2a1 = __builtin_amdgcn_mfma_i32_16x16x64_i8(qM2[1][2], kB[cb][2], m2a1, 0, 0, 0);
            m2b0 = __builtin_amdgcn_mfma_i32_16x16x64_i8(qM2[0][3], kB[cb][3], m2b0, 0, 0, 0);
            m2b1 = __builtin_amdgcn_mfma_i32_16x16x64_i8(qM2[1][3], kB[cb][3], m2b1, 0, 0, 0);

            const int col = gt * 16 + l16;
#pragma unroll
            for (int r = 0; r < 4; r++) {
                int fa = p1a[r] * 256 + m2a0[r] + m2b0[r];
                int fb = p1b[r] * 256 + m2a1[r] + m2b1[r];
                atomicAdd(&Sx[lq * 4 + r][col],      (unsigned)fa);
                atomicAdd(&Sx[16 + lq * 4 + r][col], (unsigned)fb);
            }
        }

        // vt kc=0 prefetch: lands during softmax
        bf16x8 vbuf[2][8];
        const ushort* vtI = vtB + (size_t)b * 2048;
#pragma unroll
        for (int nt = 0; nt < 8; nt++)
            vbuf[0][nt] = *(const bf16x8*)(vtI + nt * 65536);

        barrier_lgkm();

        // ---- softmax: thread (row, c0) owns cols [8c0, 8c0+8) ----
        {
            const int row = tid >> 4;
            const int c0  = tid & 15;
            i32x4 w0 = *(const i32x4*)&Sx[row][8 * c0];
            i32x4 w1 = *(const i32x4*)&Sx[row][8 * c0 + 4];
            // zero for next iteration (exclusive ownership, ordered by barrier2)
            *(i32x4*)&Sx[row][8 * c0]     = (i32x4){0,0,0,0};
            *(i32x4*)&Sx[row][8 * c0 + 4] = (i32x4){0,0,0,0};
            float sv[8];
#pragma unroll
            for (int j = 0; j < 4; j++) {
                sv[j]     = (float)w0[j] * SC2;
                sv[4 + j] = (float)w1[j] * SC2;
            }
            float mloc = sv[0];
#pragma unroll
            for (int j = 1; j < 8; j++) mloc = fmaxf(mloc, sv[j]);
#pragma unroll
            for (int off = 8; off >= 1; off >>= 1)
                mloc = fmaxf(mloc, __shfl_xor(mloc, off));
            float m_old = m_s[row];
            float m_new = fmaxf(m_old, mloc);
            float psum = 0.f;
            bf16x8 pb;
#pragma unroll
            for (int j = 0; j < 8; j++) {
                float p = __expf(sv[j] - m_new);
                psum += p;
                pb[j] = (short)f2bf(p);
            }
            *(bf16x8*)&Pt2[b & 1][pidx(row, 8 * c0)] = pb;
#pragma unroll
            for (int off = 8; off >= 1; off >>= 1)
                psum += __shfl_xor(psum, off);
            if (c0 == 0) {
                float sc = __expf(m_old - m_new);
                l_s[row] = l_s[row] * sc + psum;
                m_s[row] = m_new;
                sc_s[row] = sc;
            }
        }
        barrier_lgkm();

        // ---- rescale O, then PV over this key-block ----
        float sc0[4], sc1[4];
#pragma unroll
        for (int r = 0; r < 4; r++) {
            sc0[r] = sc_s[lq * 4 + r];
            sc1[r] = sc_s[16 + lq * 4 + r];
        }
#pragma unroll
        for (int nt = 0; nt < 8; nt++)
#pragma unroll
            for (int r = 0; r < 4; r++) {
                Oacc[0][nt][r] *= sc0[r];
                Oacc[1][nt][r] *= sc1[r];
            }

        const ushort* PtC = &Pt2[b & 1][0];
#pragma unroll
        for (int kc = 0; kc < 4; kc++) {
            if (kc < 3) {
#pragma unroll
                for (int nt = 0; nt < 8; nt++)
                    vbuf[(kc + 1) & 1][nt] = *(const bf16x8*)(vtI + nt * 65536 + (kc + 1) * 512);
            }
            bf16x8 pa0 = *(const bf16x8*)&PtC[pidx(l16, kc * 32 + lq * 8)];
            bf16x8 pa1 = *(const bf16x8*)&PtC[pidx(16 + l16, kc * 32 + lq * 8)];
#pragma unroll
            for (int nt = 0; nt < 8; nt++) {
                Oacc[0][nt] = __builtin_amdgcn_mfma_f32_16x16x32_bf16(pa0, vbuf[kc & 1][nt], Oacc[0][nt], 0, 0, 0);
                Oacc[1][nt] = __builtin_amdgcn_mfma_f32_16x16x32_bf16(pa1, vbuf[kc & 1][nt], Oacc[1][nt], 0, 0, 0);
            }
        }
    }
    __syncthreads();

    // ---- epilogue: normalize by l and store ----
    float li0[4], li1[4];
#pragma unroll
    for (int r = 0; r < 4; r++) {
        li0[r] = 1.f / l_s[lq * 4 + r];
        li1[r] = 1.f / l_s[16 + lq * 4 + r];
    }
#pragma unroll
    for (int nt = 0; nt < 8; nt++) {
#pragma unroll
        for (int r = 0; r < 4; r++) {
            int col = wave * 128 + nt * 16 + l16;
            int rowA = row0 + lq * 4 + r;
            out[(size_t)rowA * DDIM + col]        = Oacc[0][nt][r] * li0[r];
            out[(size_t)(rowA + 16) * DDIM + col] = Oacc[1][nt][r] * li1[r];
        }
    }
}

extern "C" void kernel_launch(void* const* d_in, const int* in_sizes, int n_in,
                              void* d_out, int out_size, void* d_ws, size_t ws_size,
                              hipStream_t stream) {
    const float* z    = (const float*)d_in[0];
    const float* keys = (const float*)d_in[1];
    const float* vals = (const float*)d_in[2];
    float* outp = (float*)d_out;

    i8* sa = (i8*)d_ws;                                    // 4 MB (P1 KH tiles)
    i8* sb = sa + (size_t)4 * 1024 * 1024;                 // 8 MB (M2 [KL,KH] tiles)
    ushort* vtw = (ushort*)(sb + (size_t)8 * 1024 * 1024); // 8 MB (V^T bf16 tiles)

    prep_ka<<<1024, 256, 0, stream>>>(keys, sa);
    prep_kb<<<2048, 256, 0, stream>>>(keys, sb);
    prep_vt<<<dim3(K_KEYS / 32, DDIM / 32), 256, 0, stream>>>(vals, vtw);
    attn_main<<<N_ROWS / BM, 512, 0, stream>>>(z, sa, sb, vtw, outp);
}

// Round 8
// 1132.883 us; speedup vs baseline: 2.9860x; 2.9770x over previous
//
#include <hip/hip_runtime.h>
#include <hip/hip_bf16.h>

typedef __attribute__((ext_vector_type(8))) short bf16x8;
typedef __attribute__((ext_vector_type(4))) float f32x4;
typedef __attribute__((ext_vector_type(4))) int   i32x4;
typedef signed char i8;

#define N_ROWS 32768
#define K_KEYS 4096
#define DDIM   1024
#define BM 32
#define BK 128
#define NBLK (K_KEYS / BK)   /* 32 */
#define SP 132               /* Sx u32 pitch: ds_add 2-way, b128 read 4-way */
#define SC2 (1.52587890625e-05f) /* 2^-16 */

__device__ __forceinline__ ushort f2bf(float f) {
    __hip_bfloat16 b = __float2bfloat16(f);
    return *(ushort*)&b;
}
__device__ __forceinline__ float bf2f(ushort u) {
    __hip_bfloat16 b = *(__hip_bfloat16*)&u;
    return __bfloat162float(b);
}
__device__ __forceinline__ int clampi(int x) { return x > 127 ? 127 : (x < -127 ? -127 : x); }

// Pt swizzle (ushort units, 8-ushort granule XORed with row&7)
__device__ __forceinline__ int pidx(int r, int c_us) { return r * 128 + (c_us ^ ((r & 7) << 3)); }

// barrier that does NOT drain vmcnt: global prefetches stay in flight.
__device__ __forceinline__ void barrier_lgkm() {
    asm volatile("s_waitcnt lgkmcnt(0)" ::: "memory");
    __builtin_amdgcn_s_barrier();
    asm volatile("" ::: "memory");
}

// ---- prep: keys -> stream A (P1 operand): KH int8, tiles (g,c)=16 keys x 64 dims ----
__global__ void prep_ka(const float* __restrict__ keys, i8* __restrict__ sa) {
    int idx  = blockIdx.x * 256 + threadIdx.x;
    int lane = idx & 63, tile = idx >> 6;        // tile = g*16 + c
    int g = tile >> 4, c = tile & 15;
    int key = g * 16 + (lane & 15);
    int d0  = c * 64 + (lane >> 4) * 16;
    const float* s = keys + (size_t)key * DDIM + d0;
    union { i32x4 v; i8 b[16]; } u;
#pragma unroll
    for (int e = 0; e < 16; e++)
        u.b[e] = (i8)clampi((int)rintf(s[e] * 16.f));
    *(i32x4*)(sa + (size_t)tile * 1024 + lane * 16) = u.v;
}

// ---- prep: keys -> stream B (M2 operand): [KL,KH] interleaved ----
// A even byte = QH pairs with B even = KL; A odd = QL pairs with B odd = KH.
__global__ void prep_kb(const float* __restrict__ keys, i8* __restrict__ sb) {
    int idx  = blockIdx.x * 256 + threadIdx.x;
    int lane = idx & 63, tile = idx >> 6;        // tile = g*32 + m
    int g = tile >> 5, m = tile & 31;
    int key = g * 16 + (lane & 15);
    int d0  = m * 32 + (lane >> 4) * 8;
    const float* s = keys + (size_t)key * DDIM + d0;
    union { i32x4 v; i8 b[16]; } u;
#pragma unroll
    for (int e = 0; e < 8; e++) {
        float q = s[e];
        int h = clampi((int)rintf(q * 16.f));
        int l = clampi((int)rintf((q - (float)h * 0.0625f) * 4096.f));
        u.b[2 * e]     = (i8)l;   // KL pairs with QH
        u.b[2 * e + 1] = (i8)h;   // KH pairs with QL
    }
    *(i32x4*)(sb + (size_t)tile * 1024 + lane * 16) = u.v;
}

// ---- prep: values fp32 [K][D] -> packed V^T bf16 fragment tiles ----
__global__ void prep_vt(const float* __restrict__ v, ushort* __restrict__ vt) {
    __shared__ float t[32][33];
    const int tk = blockIdx.x;
    const int td = blockIdx.y;
    const int tx = threadIdx.x & 31;
    const int ty = threadIdx.x >> 5;
#pragma unroll
    for (int r = 0; r < 4; r++) {
        int k = tk * 32 + ty + 8 * r;
        t[ty + 8 * r][tx] = v[(size_t)k * DDIM + td * 32 + tx];
    }
    __syncthreads();
    if (threadIdx.x < 128) {
        int s    = threadIdx.x >> 6;
        int lane = threadIdx.x & 63;
        int l16  = lane & 15, lq = lane >> 4;
        int dg   = td * 2 + s;
        int dl   = s * 16 + l16;
        bf16x8 o;
#pragma unroll
        for (int e = 0; e < 8; e++)
            o[e] = (short)f2bf(t[lq * 8 + e][dl]);
        *(bf16x8*)(vt + ((size_t)dg * 128 + tk) * 512 + lane * 8) = o;
    }
}

// Fused flash kernel: d-split int8 QK, fixed-point ds_add S-reduction.
// __launch_bounds__(512, 2): the proven config (rounds 2-5) — compiler
// allocates the natural 128 VGPR, no spills. Do NOT hint higher occupancy:
// round 6/7 showed min_waves=4 (or waves_per_eu(4,4)) flips the allocator
// into a 64-VGPR regime that spills Q/K/Oacc to scratch (6.3 GB HBM, 3x slower).
// With LDS=34KB, 2 blocks/CU fit at 128 VGPR by construction.
__launch_bounds__(512, 2)
__global__ void attn_main(const float* __restrict__ z,
                          const i8* __restrict__ sa,
                          const i8* __restrict__ sb,
                          const ushort* __restrict__ vtp,
                          float* __restrict__ out) {
    __shared__ unsigned Sx[BM][SP];       // 16896 B, fixed-point 2^-16
    __shared__ ushort Pt2[2][BM * 128];   // 16384 B
    __shared__ float  m_s[BM], l_s[BM], sc_s[BM];

    const int tid  = threadIdx.x;
    const int wave = tid >> 6;
    const int lane = tid & 63;
    const int l16  = lane & 15;
    const int lq   = lane >> 4;
    const int row0 = blockIdx.x * BM;

    // ---- Q int8-split fragments for this wave's 128 dims, in registers ----
    i32x4 qP1[2][2], qM2[2][4];
#pragma unroll
    for (int rg = 0; rg < 2; rg++) {
        int row = row0 + rg * 16 + l16;
        const float* zr = z + (size_t)row * DDIM + wave * 128;
#pragma unroll
        for (int c = 0; c < 2; c++) {
            union { i32x4 v; i8 b[16]; } u;
            const float* s = zr + c * 64 + lq * 16;
#pragma unroll
            for (int e = 0; e < 16; e++)
                u.b[e] = (i8)clampi((int)rintf(s[e] * 16.f));
            qP1[rg][c] = u.v;
        }
#pragma unroll
        for (int m = 0; m < 4; m++) {
            union { i32x4 v; i8 b[16]; } u;
            const float* s = zr + m * 32 + lq * 8;
#pragma unroll
            for (int e = 0; e < 8; e++) {
                float q = s[e];
                int h = clampi((int)rintf(q * 16.f));
                int l = clampi((int)rintf((q - (float)h * 0.0625f) * 4096.f));
                u.b[2 * e]     = (i8)h;   // QH pairs with KL
                u.b[2 * e + 1] = (i8)l;   // QL pairs with KH
            }
            qM2[rg][m] = u.v;
        }
    }
    if (tid < BM) { m_s[tid] = -1e30f; l_s[tid] = 0.f; }
    // zero the S accumulator
    for (int i = tid; i < BM * SP; i += 512)
        ((unsigned*)Sx)[i] = 0u;
    __syncthreads();

    f32x4 Oacc[2][8];
#pragma unroll
    for (int mt = 0; mt < 2; mt++)
#pragma unroll
        for (int nt = 0; nt < 8; nt++)
            Oacc[mt][nt] = (f32x4){0.f, 0.f, 0.f, 0.f};

    const i8* saB = sa + (size_t)wave * 2048 + lane * 16;
    const i8* sbB = sb + (size_t)wave * 4096 + lane * 16;
    const ushort* vtB = vtp + (size_t)wave * 524288 + lane * 8;

    i32x4 kA[2][2], kB[2][4];
#define LOADK8(gg, buf)                                                        \
    do {                                                                       \
        const i8* _a = saB + (size_t)(gg) * 16384;                             \
        const i8* _b = sbB + (size_t)(gg) * 32768;                             \
        kA[buf][0] = *(const i32x4*)_a;                                        \
        kA[buf][1] = *(const i32x4*)(_a + 1024);                               \
        kB[buf][0] = *(const i32x4*)_b;                                        \
        kB[buf][1] = *(const i32x4*)(_b + 1024);                               \
        kB[buf][2] = *(const i32x4*)(_b + 2048);                               \
        kB[buf][3] = *(const i32x4*)(_b + 3072);                               \
    } while (0)

    LOADK8(0, 0);

    for (int b = 0; b < NBLK; b++) {
        // ---- QK^T: per key-tile gt (16 keys), 12 int8 MFMAs over 128 dims ----
#pragma unroll
        for (int gt = 0; gt < 8; gt++) {
            const int cb = gt & 1, nb2 = cb ^ 1;
            if (gt < 7) {
                LOADK8(8 * b + gt + 1, nb2);
            } else {
                int gn = (b + 1 < NBLK) ? 8 * (b + 1) : 8 * b;
                LOADK8(gn, nb2);
            }
            i32x4 p1a = {0,0,0,0}, p1b = {0,0,0,0};
            i32x4 m2a0 = {0,0,0,0}, m2a1 = {0,0,0,0};
            i32x4 m2b0 = {0,0,0,0}, m2b1 = {0,0,0,0};
            p1a  = __builtin_amdgcn_mfma_i32_16x16x64_i8(qP1[0][0], kA[cb][0], p1a, 0, 0, 0);
            p1b  = __builtin_amdgcn_mfma_i32_16x16x64_i8(qP1[1][0], kA[cb][0], p1b, 0, 0, 0);
            m2a0 = __builtin_amdgcn_mfma_i32_16x16x64_i8(qM2[0][0], kB[cb][0], m2a0, 0, 0, 0);
            m2a1 = __builtin_amdgcn_mfma_i32_16x16x64_i8(qM2[1][0], kB[cb][0], m2a1, 0, 0, 0);
            m2b0 = __builtin_amdgcn_mfma_i32_16x16x64_i8(qM2[0][1], kB[cb][1], m2b0, 0, 0, 0);
            m2b1 = __builtin_amdgcn_mfma_i32_16x16x64_i8(qM2[1][1], kB[cb][1], m2b1, 0, 0, 0);
            p1a  = __builtin_amdgcn_mfma_i32_16x16x64_i8(qP1[0][1], kA[cb][1], p1a, 0, 0, 0);
            p1b  = __builtin_amdgcn_mfma_i32_16x16x64_i8(qP1[1][1], kA[cb][1], p1b, 0, 0, 0);
            m2a0 = __builtin_amdgcn_mfma_i32_16x16x64_i8(qM2[0][2], kB[cb][2], m2a0, 0, 0, 0);
            m2a1 = __builtin_amdgcn_mfma_i32_16x16x64_i8(qM2[1][2], kB[cb][2], m2a1, 0, 0, 0);
            m2b0 = __builtin_amdgcn_mfma_i32_16x16x64_i8(qM2[0][3], kB[cb][3], m2b0, 0, 0, 0);
            m2b1 = __builtin_amdgcn_mfma_i32_16x16x64_i8(qM2[1][3], kB[cb][3], m2b1, 0, 0, 0);

            const int col = gt * 16 + l16;
#pragma unroll
            for (int r = 0; r < 4; r++) {
                int fa = p1a[r] * 256 + m2a0[r] + m2b0[r];
                int fb = p1b[r] * 256 + m2a1[r] + m2b1[r];
                atomicAdd(&Sx[lq * 4 + r][col],      (unsigned)fa);
                atomicAdd(&Sx[16 + lq * 4 + r][col], (unsigned)fb);
            }
        }

        // vt kc=0 prefetch: lands during softmax
        bf16x8 vbuf[2][8];
        const ushort* vtI = vtB + (size_t)b * 2048;
#pragma unroll
        for (int nt = 0; nt < 8; nt++)
            vbuf[0][nt] = *(const bf16x8*)(vtI + nt * 65536);

        barrier_lgkm();

        // ---- softmax: thread (row, c0) owns cols [8c0, 8c0+8) ----
        {
            const int row = tid >> 4;
            const int c0  = tid & 15;
            i32x4 w0 = *(const i32x4*)&Sx[row][8 * c0];
            i32x4 w1 = *(const i32x4*)&Sx[row][8 * c0 + 4];
            // zero for next iteration (exclusive ownership, ordered by barrier2)
            *(i32x4*)&Sx[row][8 * c0]     = (i32x4){0,0,0,0};
            *(i32x4*)&Sx[row][8 * c0 + 4] = (i32x4){0,0,0,0};
            float sv[8];
#pragma unroll
            for (int j = 0; j < 4; j++) {
                sv[j]     = (float)w0[j] * SC2;
                sv[4 + j] = (float)w1[j] * SC2;
            }
            float mloc = sv[0];
#pragma unroll
            for (int j = 1; j < 8; j++) mloc = fmaxf(mloc, sv[j]);
#pragma unroll
            for (int off = 8; off >= 1; off >>= 1)
                mloc = fmaxf(mloc, __shfl_xor(mloc, off));
            float m_old = m_s[row];
            float m_new = fmaxf(m_old, mloc);
            float psum = 0.f;
            bf16x8 pb;
#pragma unroll
            for (int j = 0; j < 8; j++) {
                float p = __expf(sv[j] - m_new);
                psum += p;
                pb[j] = (short)f2bf(p);
            }
            *(bf16x8*)&Pt2[b & 1][pidx(row, 8 * c0)] = pb;
#pragma unroll
            for (int off = 8; off >= 1; off >>= 1)
                psum += __shfl_xor(psum, off);
            if (c0 == 0) {
                float sc = __expf(m_old - m_new);
                l_s[row] = l_s[row] * sc + psum;
                m_s[row] = m_new;
                sc_s[row] = sc;
            }
        }
        barrier_lgkm();

        // ---- rescale O, then PV over this key-block ----
        float sc0[4], sc1[4];
#pragma unroll
        for (int r = 0; r < 4; r++) {
            sc0[r] = sc_s[lq * 4 + r];
            sc1[r] = sc_s[16 + lq * 4 + r];
        }
#pragma unroll
        for (int nt = 0; nt < 8; nt++)
#pragma unroll
            for (int r = 0; r < 4; r++) {
                Oacc[0][nt][r] *= sc0[r];
                Oacc[1][nt][r] *= sc1[r];
            }

        const ushort* PtC = &Pt2[b & 1][0];
#pragma unroll
        for (int kc = 0; kc < 4; kc++) {
            if (kc < 3) {
#pragma unroll
                for (int nt = 0; nt < 8; nt++)
                    vbuf[(kc + 1) & 1][nt] = *(const bf16x8*)(vtI + nt * 65536 + (kc + 1) * 512);
            }
            bf16x8 pa0 = *(const bf16x8*)&PtC[pidx(l16, kc * 32 + lq * 8)];
            bf16x8 pa1 = *(const bf16x8*)&PtC[pidx(16 + l16, kc * 32 + lq * 8)];
#pragma unroll
            for (int nt = 0; nt < 8; nt++) {
                Oacc[0][nt] = __builtin_amdgcn_mfma_f32_16x16x32_bf16(pa0, vbuf[kc & 1][nt], Oacc[0][nt], 0, 0, 0);
                Oacc[1][nt] = __builtin_amdgcn_mfma_f32_16x16x32_bf16(pa1, vbuf[kc & 1][nt], Oacc[1][nt], 0, 0, 0);
            }
        }
    }
    __syncthreads();

    // ---- epilogue: normalize by l and store ----
    float li0[4], li1[4];
#pragma unroll
    for (int r = 0; r < 4; r++) {
        li0[r] = 1.f / l_s[lq * 4 + r];
        li1[r] = 1.f / l_s[16 + lq * 4 + r];
    }
#pragma unroll
    for (int nt = 0; nt < 8; nt++) {
#pragma unroll
        for (int r = 0; r < 4; r++) {
            int col = wave * 128 + nt * 16 + l16;
            int rowA = row0 + lq * 4 + r;
            out[(size_t)rowA * DDIM + col]        = Oacc[0][nt][r] * li0[r];
            out[(size_t)(rowA + 16) * DDIM + col] = Oacc[1][nt][r] * li1[r];
        }
    }
}

extern "C" void kernel_launch(void* const* d_in, const int* in_sizes, int n_in,
                              void* d_out, int out_size, void* d_ws, size_t ws_size,
                              hipStream_t stream) {
    const float* z    = (const float*)d_in[0];
    const float* keys = (const float*)d_in[1];
    const float* vals = (const float*)d_in[2];
    float* outp = (float*)d_out;

    i8* sa = (i8*)d_ws;                                    // 4 MB (P1 KH tiles)
    i8* sb = sa + (size_t)4 * 1024 * 1024;                 // 8 MB (M2 [KL,KH] tiles)
    ushort* vtw = (ushort*)(sb + (size_t)8 * 1024 * 1024); // 8 MB (V^T bf16 tiles)

    prep_ka<<<1024, 256, 0, stream>>>(keys, sa);
    prep_kb<<<2048, 256, 0, stream>>>(keys, sb);
    prep_vt<<<dim3(K_KEYS / 32, DDIM / 32), 256, 0, stream>>>(vals, vtw);
    attn_main<<<N_ROWS / BM, 512, 0, stream>>>(z, sa, sb, vtw, outp);
}

// Round 9
// 1076.817 us; speedup vs baseline: 3.1415x; 1.0521x over previous
//
#include <hip/hip_runtime.h>
#include <hip/hip_bf16.h>

typedef __attribute__((ext_vector_type(8))) short bf16x8;
typedef __attribute__((ext_vector_type(4))) float f32x4;
typedef __attribute__((ext_vector_type(4))) int   i32x4;
typedef signed char i8;

#define N_ROWS 32768
#define K_KEYS 4096
#define DDIM   1024
#define BM 32
#define BK 128
#define NBLK (K_KEYS / BK)   /* 32 */
#define SP 132               /* Sx u32 pitch */
#define SC2 (1.52587890625e-05f) /* 2^-16 */

__device__ __forceinline__ ushort f2bf(float f) {
    __hip_bfloat16 b = __float2bfloat16(f);
    return *(ushort*)&b;
}
__device__ __forceinline__ float bf2f(ushort u) {
    __hip_bfloat16 b = *(__hip_bfloat16*)&u;
    return __bfloat162float(b);
}
__device__ __forceinline__ int clampi(int x) { return x > 127 ? 127 : (x < -127 ? -127 : x); }

// Pt swizzle (ushort units, 8-ushort granule XORed with row&7)
__device__ __forceinline__ int pidx(int r, int c_us) { return r * 128 + (c_us ^ ((r & 7) << 3)); }

// barrier that does NOT drain vmcnt: global prefetches stay in flight.
__device__ __forceinline__ void barrier_lgkm() {
    asm volatile("s_waitcnt lgkmcnt(0)" ::: "memory");
    __builtin_amdgcn_s_barrier();
    asm volatile("" ::: "memory");
}

// ---- prep: keys -> single K stream: [KL,KH] interleaved, tiles (g,m)=16 keys x 32 dims ----
// Even byte KL (pairs with QH for the cross term), odd byte KH (pairs with QL,
// and with the masked [0,QH] operand for the exact P1 = sum QH*KH pass).
__global__ void prep_kb(const float* __restrict__ keys, i8* __restrict__ sb) {
    int idx  = blockIdx.x * 256 + threadIdx.x;
    int lane = idx & 63, tile = idx >> 6;        // tile = g*32 + m
    int g = tile >> 5, m = tile & 31;
    int key = g * 16 + (lane & 15);
    int d0  = m * 32 + (lane >> 4) * 8;
    const float* s = keys + (size_t)key * DDIM + d0;
    union { i32x4 v; i8 b[16]; } u;
#pragma unroll
    for (int e = 0; e < 8; e++) {
        float q = s[e];
        int h = clampi((int)rintf(q * 16.f));
        int l = clampi((int)rintf((q - (float)h * 0.0625f) * 4096.f));
        u.b[2 * e]     = (i8)l;   // KL pairs with QH
        u.b[2 * e + 1] = (i8)h;   // KH pairs with QL / masked-QH
    }
    *(i32x4*)(sb + (size_t)tile * 1024 + lane * 16) = u.v;
}

// ---- prep: values fp32 [K][D] -> packed V^T bf16 fragment tiles ----
__global__ void prep_vt(const float* __restrict__ v, ushort* __restrict__ vt) {
    __shared__ float t[32][33];
    const int tk = blockIdx.x;
    const int td = blockIdx.y;
    const int tx = threadIdx.x & 31;
    const int ty = threadIdx.x >> 5;
#pragma unroll
    for (int r = 0; r < 4; r++) {
        int k = tk * 32 + ty + 8 * r;
        t[ty + 8 * r][tx] = v[(size_t)k * DDIM + td * 32 + tx];
    }
    __syncthreads();
    if (threadIdx.x < 128) {
        int s    = threadIdx.x >> 6;
        int lane = threadIdx.x & 63;
        int l16  = lane & 15, lq = lane >> 4;
        int dg   = td * 2 + s;
        int dl   = s * 16 + l16;
        bf16x8 o;
#pragma unroll
        for (int e = 0; e < 8; e++)
            o[e] = (short)f2bf(t[lq * 8 + e][dl]);
        *(bf16x8*)(vt + ((size_t)dg * 128 + tk) * 512 + lane * 8) = o;
    }
}

// Fused flash kernel: d-split int8 QK (single merged K stream), fixed-point
// ds_add S-reduction. __launch_bounds__(512,2): proven no-spill config.
// NOTE occupancy is register-structural at 1 block/CU (VGPR+AGPR ~184/wave);
// the lever here is stream bytes: 80 -> 64 KB per wave per K-iteration.
__launch_bounds__(512, 2)
__global__ void attn_main(const float* __restrict__ z,
                          const i8* __restrict__ sb,
                          const ushort* __restrict__ vtp,
                          float* __restrict__ out) {
    __shared__ unsigned Sx[BM][SP];       // 16896 B, fixed-point 2^-16
    __shared__ ushort Pt2[2][BM * 128];   // 16384 B
    __shared__ float  m_s[BM], l_s[BM], sc_s[BM];

    const int tid  = threadIdx.x;
    const int wave = tid >> 6;
    const int lane = tid & 63;
    const int l16  = lane & 15;
    const int lq   = lane >> 4;
    const int row0 = blockIdx.x * BM;

    // ---- Q fragments for this wave's 128 dims, in registers ----
    // qM2[rg][m]:  even byte QH, odd byte QL  (cross terms vs [KL,KH])
    // qP1z[rg][m]: even byte 0,  odd byte QH  (P1 = sum QH*KH, exact)
    i32x4 qM2[2][4], qP1z[2][4];
#pragma unroll
    for (int rg = 0; rg < 2; rg++) {
        int row = row0 + rg * 16 + l16;
        const float* zr = z + (size_t)row * DDIM + wave * 128;
#pragma unroll
        for (int m = 0; m < 4; m++) {
            union { i32x4 v; i8 b[16]; } u, w;
            const float* s = zr + m * 32 + lq * 8;
#pragma unroll
            for (int e = 0; e < 8; e++) {
                float q = s[e];
                int h = clampi((int)rintf(q * 16.f));
                int l = clampi((int)rintf((q - (float)h * 0.0625f) * 4096.f));
                u.b[2 * e]     = (i8)h;
                u.b[2 * e + 1] = (i8)l;
                w.b[2 * e]     = 0;
                w.b[2 * e + 1] = (i8)h;
            }
            qM2[rg][m]  = u.v;
            qP1z[rg][m] = w.v;
        }
    }
    if (tid < BM) { m_s[tid] = -1e30f; l_s[tid] = 0.f; }
    for (int i = tid; i < BM * SP; i += 512)
        ((unsigned*)Sx)[i] = 0u;
    __syncthreads();

    f32x4 Oacc[2][8];
#pragma unroll
    for (int mt = 0; mt < 2; mt++)
#pragma unroll
        for (int nt = 0; nt < 8; nt++)
            Oacc[mt][nt] = (f32x4){0.f, 0.f, 0.f, 0.f};

    const i8* sbB = sb + (size_t)wave * 4096 + lane * 16;
    const ushort* vtB = vtp + (size_t)wave * 524288 + lane * 8;

    i32x4 kB[2][4];
#define LOADKB(gg, buf)                                                        \
    do {                                                                       \
        const i8* _b = sbB + (size_t)(gg) * 32768;                             \
        kB[buf][0] = *(const i32x4*)_b;                                        \
        kB[buf][1] = *(const i32x4*)(_b + 1024);                               \
        kB[buf][2] = *(const i32x4*)(_b + 2048);                               \
        kB[buf][3] = *(const i32x4*)(_b + 3072);                               \
    } while (0)

    LOADKB(0, 0);

    for (int b = 0; b < NBLK; b++) {
        // ---- QK^T: per key-tile gt (16 keys), 16 int8 MFMAs over 128 dims ----
#pragma unroll
        for (int gt = 0; gt < 8; gt++) {
            const int cb = gt & 1, nb2 = cb ^ 1;
            if (gt < 7) {
                LOADKB(8 * b + gt + 1, nb2);
            } else {
                int gn = (b + 1 < NBLK) ? 8 * (b + 1) : 8 * b;
                LOADKB(gn, nb2);
            }
            i32x4 p1a = {0,0,0,0}, p1b = {0,0,0,0};
            i32x4 m2ae = {0,0,0,0}, m2ao = {0,0,0,0};
            i32x4 m2be = {0,0,0,0}, m2bo = {0,0,0,0};
            // m = 0
            m2ae = __builtin_amdgcn_mfma_i32_16x16x64_i8(qM2[0][0],  kB[cb][0], m2ae, 0, 0, 0);
            m2be = __builtin_amdgcn_mfma_i32_16x16x64_i8(qM2[1][0],  kB[cb][0], m2be, 0, 0, 0);
            p1a  = __builtin_amdgcn_mfma_i32_16x16x64_i8(qP1z[0][0], kB[cb][0], p1a,  0, 0, 0);
            p1b  = __builtin_amdgcn_mfma_i32_16x16x64_i8(qP1z[1][0], kB[cb][0], p1b,  0, 0, 0);
            // m = 1
            m2ao = __builtin_amdgcn_mfma_i32_16x16x64_i8(qM2[0][1],  kB[cb][1], m2ao, 0, 0, 0);
            m2bo = __builtin_amdgcn_mfma_i32_16x16x64_i8(qM2[1][1],  kB[cb][1], m2bo, 0, 0, 0);
            p1a  = __builtin_amdgcn_mfma_i32_16x16x64_i8(qP1z[0][1], kB[cb][1], p1a,  0, 0, 0);
            p1b  = __builtin_amdgcn_mfma_i32_16x16x64_i8(qP1z[1][1], kB[cb][1], p1b,  0, 0, 0);
            // m = 2
            m2ae = __builtin_amdgcn_mfma_i32_16x16x64_i8(qM2[0][2],  kB[cb][2], m2ae, 0, 0, 0);
            m2be = __builtin_amdgcn_mfma_i32_16x16x64_i8(qM2[1][2],  kB[cb][2], m2be, 0, 0, 0);
            p1a  = __builtin_amdgcn_mfma_i32_16x16x64_i8(qP1z[0][2], kB[cb][2], p1a,  0, 0, 0);
            p1b  = __builtin_amdgcn_mfma_i32_16x16x64_i8(qP1z[1][2], kB[cb][2], p1b,  0, 0, 0);
            // m = 3
            m2ao = __builtin_amdgcn_mfma_i32_16x16x64_i8(qM2[0][3],  kB[cb][3], m2ao, 0, 0, 0);
            m2bo = __builtin_amdgcn_mfma_i32_16x16x64_i8(qM2[1][3],  kB[cb][3], m2bo, 0, 0, 0);
            p1a  = __builtin_amdgcn_mfma_i32_16x16x64_i8(qP1z[0][3], kB[cb][3], p1a,  0, 0, 0);
            p1b  = __builtin_amdgcn_mfma_i32_16x16x64_i8(qP1z[1][3], kB[cb][3], p1b,  0, 0, 0);

            const int col = gt * 16 + l16;
#pragma unroll
            for (int r = 0; r < 4; r++) {
                int fa = p1a[r] * 256 + m2ae[r] + m2ao[r];
                int fb = p1b[r] * 256 + m2be[r] + m2bo[r];
                atomicAdd(&Sx[lq * 4 + r][col],      (unsigned)fa);
                atomicAdd(&Sx[16 + lq * 4 + r][col], (unsigned)fb);
            }
        }

        // vt kc=0 prefetch: lands during softmax
        bf16x8 vbuf[2][8];
        const ushort* vtI = vtB + (size_t)b * 2048;
#pragma unroll
        for (int nt = 0; nt < 8; nt++)
            vbuf[0][nt] = *(const bf16x8*)(vtI + nt * 65536);

        barrier_lgkm();

        // ---- softmax: thread (row, c0) owns cols [8c0, 8c0+8) ----
        {
            const int row = tid >> 4;
            const int c0  = tid & 15;
            i32x4 w0 = *(const i32x4*)&Sx[row][8 * c0];
            i32x4 w1 = *(const i32x4*)&Sx[row][8 * c0 + 4];
            *(i32x4*)&Sx[row][8 * c0]     = (i32x4){0,0,0,0};
            *(i32x4*)&Sx[row][8 * c0 + 4] = (i32x4){0,0,0,0};
            float sv[8];
#pragma unroll
            for (int j = 0; j < 4; j++) {
                sv[j]     = (float)w0[j] * SC2;
                sv[4 + j] = (float)w1[j] * SC2;
            }
            float mloc = sv[0];
#pragma unroll
            for (int j = 1; j < 8; j++) mloc = fmaxf(mloc, sv[j]);
#pragma unroll
            for (int off = 8; off >= 1; off >>= 1)
                mloc = fmaxf(mloc, __shfl_xor(mloc, off));
            float m_old = m_s[row];
            float m_new = fmaxf(m_old, mloc);
            float psum = 0.f;
            bf16x8 pb;
#pragma unroll
            for (int j = 0; j < 8; j++) {
                float p = __expf(sv[j] - m_new);
                psum += p;
                pb[j] = (short)f2bf(p);
            }
            *(bf16x8*)&Pt2[b & 1][pidx(row, 8 * c0)] = pb;
#pragma unroll
            for (int off = 8; off >= 1; off >>= 1)
                psum += __shfl_xor(psum, off);
            if (c0 == 0) {
                float sc = __expf(m_old - m_new);
                l_s[row] = l_s[row] * sc + psum;
                m_s[row] = m_new;
                sc_s[row] = sc;
            }
        }
        barrier_lgkm();

        // ---- rescale O, then PV over this key-block ----
        float sc0[4], sc1[4];
#pragma unroll
        for (int r = 0; r < 4; r++) {
            sc0[r] = sc_s[lq * 4 + r];
            sc1[r] = sc_s[16 + lq * 4 + r];
        }
#pragma unroll
        for (int nt = 0; nt < 8; nt++)
#pragma unroll
            for (int r = 0; r < 4; r++) {
                Oacc[0][nt][r] *= sc0[r];
                Oacc[1][nt][r] *= sc1[r];
            }

        const ushort* PtC = &Pt2[b & 1][0];
#pragma unroll
        for (int kc = 0; kc < 4; kc++) {
            if (kc < 3) {
#pragma unroll
                for (int nt = 0; nt < 8; nt++)
                    vbuf[(kc + 1) & 1][nt] = *(const bf16x8*)(vtI + nt * 65536 + (kc + 1) * 512);
            }
            bf16x8 pa0 = *(const bf16x8*)&PtC[pidx(l16, kc * 32 + lq * 8)];
            bf16x8 pa1 = *(const bf16x8*)&PtC[pidx(16 + l16, kc * 32 + lq * 8)];
#pragma unroll
            for (int nt = 0; nt < 8; nt++) {
                Oacc[0][nt] = __builtin_amdgcn_mfma_f32_16x16x32_bf16(pa0, vbuf[kc & 1][nt], Oacc[0][nt], 0, 0, 0);
                Oacc[1][nt] = __builtin_amdgcn_mfma_f32_16x16x32_bf16(pa1, vbuf[kc & 1][nt], Oacc[1][nt], 0, 0, 0);
            }
        }
    }
    __syncthreads();

    // ---- epilogue: normalize by l and store ----
    float li0[4], li1[4];
#pragma unroll
    for (int r = 0; r < 4; r++) {
        li0[r] = 1.f / l_s[lq * 4 + r];
        li1[r] = 1.f / l_s[16 + lq * 4 + r];
    }
#pragma unroll
    for (int nt = 0; nt < 8; nt++) {
#pragma unroll
        for (int r = 0; r < 4; r++) {
            int col = wave * 128 + nt * 16 + l16;
            int rowA = row0 + lq * 4 + r;
            out[(size_t)rowA * DDIM + col]        = Oacc[0][nt][r] * li0[r];
            out[(size_t)(rowA + 16) * DDIM + col] = Oacc[1][nt][r] * li1[r];
        }
    }
}

extern "C" void kernel_launch(void* const* d_in, const int* in_sizes, int n_in,
                              void* d_out, int out_size, void* d_ws, size_t ws_size,
                              hipStream_t stream) {
    const float* z    = (const float*)d_in[0];
    const float* keys = (const float*)d_in[1];
    const float* vals = (const float*)d_in[2];
    float* outp = (float*)d_out;

    i8* sb = (i8*)d_ws;                                    // 8 MB (merged [KL,KH] tiles)
    ushort* vtw = (ushort*)(sb + (size_t)8 * 1024 * 1024); // 8 MB (V^T bf16 tiles)

    prep_kb<<<2048, 256, 0, stream>>>(keys, sb);
    prep_vt<<<dim3(K_KEYS / 32, DDIM / 32), 256, 0, stream>>>(vals, vtw);
    attn_main<<<N_ROWS / BM, 512, 0, stream>>>(z, sb, vtw, outp);
}